// Round 1
// baseline (403.387 us; speedup 1.0000x reference)
//
#include <hip/hip_runtime.h>
#include <math.h>

#define NROWS 8192
#define NCOLS 8192
#define RB 64
#define CB 64

// ---------------------------------------------------------------------------
// Kernel 1: row-block partial sums.  Grid (8 col-tiles, 128 row-chunks),
// 256 threads.  Each thread owns 4 consecutive columns (float4 loads,
// perfectly coalesced) and walks 64 rows.  row_ids is sorted, so the block id
// only changes a handful of times per chunk -> register accumulate, flush via
// atomicAdd into s1[64][8192] on change.
// ---------------------------------------------------------------------------
__global__ __launch_bounds__(256) void block_rowsum_kernel(
    const float* __restrict__ X,
    const int*   __restrict__ row_ids,
    float*       __restrict__ s1)
{
    __shared__ int rids[64];
    const int tid = threadIdx.x;
    const int r0  = blockIdx.y * 64;
    const int c   = blockIdx.x * 1024 + tid * 4;

    if (tid < 64) rids[tid] = row_ids[r0 + tid];
    __syncthreads();

    float4 acc = make_float4(0.f, 0.f, 0.f, 0.f);
    int cur = rids[0];
    const float* Xp = X + (size_t)r0 * NCOLS + c;

    #pragma unroll 4
    for (int i = 0; i < 64; ++i) {
        const int rb = rids[i];                    // wave-uniform branch
        if (rb != cur) {
            float* d = s1 + (size_t)cur * NCOLS + c;
            atomicAdd(d + 0, acc.x); atomicAdd(d + 1, acc.y);
            atomicAdd(d + 2, acc.z); atomicAdd(d + 3, acc.w);
            acc = make_float4(0.f, 0.f, 0.f, 0.f);
            cur = rb;
        }
        const float4 v = *(const float4*)(Xp + (size_t)i * NCOLS);
        acc.x += v.x; acc.y += v.y; acc.z += v.z; acc.w += v.w;
    }
    float* d = s1 + (size_t)cur * NCOLS + c;
    atomicAdd(d + 0, acc.x); atomicAdd(d + 1, acc.y);
    atomicAdd(d + 2, acc.z); atomicAdd(d + 3, acc.w);
}

// ---------------------------------------------------------------------------
// Kernel 2: segment counts + cumsums.  Block 0 -> rows, block 1 -> cols.
// Cumsum written to d_out as fp32 numeric values (harness reads flat fp32).
// fp32 counts stashed in ws for kernel 3.
// ---------------------------------------------------------------------------
__global__ __launch_bounds__(256) void counts_kernel(
    const int* __restrict__ row_ids,
    const int* __restrict__ col_ids,
    float*     __restrict__ out,     // d_out
    float*     __restrict__ cnts)    // ws: [0..63] row counts, [64..127] col counts
{
    __shared__ int cnt[64];
    const int tid = threadIdx.x;
    const int* ids = (blockIdx.x == 0) ? row_ids : col_ids;
    const int n = (blockIdx.x == 0) ? NROWS : NCOLS;

    if (tid < 64) cnt[tid] = 0;
    __syncthreads();
    for (int i = tid; i < n; i += blockDim.x)
        atomicAdd(&cnt[ids[i]], 1);
    __syncthreads();

    if (tid < 64) cnts[blockIdx.x * 64 + tid] = (float)cnt[tid];
    if (tid == 0) {
        float* obase = out + RB * CB + blockIdx.x * (RB + 1);
        int c = 0;
        obase[0] = 0.0f;
        for (int i = 0; i < 64; ++i) { c += cnt[i]; obase[i + 1] = (float)c; }
    }
}

// ---------------------------------------------------------------------------
// Kernel 3: reduce s1 over sorted col_ids -> block sums, then per-cell
// mean -> tiny MLP -> sigmoid.  One WG per row-block.
// ---------------------------------------------------------------------------
__global__ __launch_bounds__(256) void colreduce_mlp_kernel(
    const float* __restrict__ s1,
    const int*   __restrict__ col_ids,
    const float* __restrict__ cnts,
    const float* __restrict__ W1, const float* __restrict__ b1,
    const float* __restrict__ W2, const float* __restrict__ b2,
    const float* __restrict__ W3, const float* __restrict__ b3,
    float*       __restrict__ out)
{
    __shared__ float acc[64];
    const int tid = threadIdx.x;
    const int rb  = blockIdx.x;

    if (tid < 64) acc[tid] = 0.0f;
    __syncthreads();

    const int c0 = tid * 32;                       // 32 consecutive cols/thread
    const float* sp = s1 + (size_t)rb * NCOLS + c0;
    int cur = col_ids[c0];
    float s = 0.f;
    for (int j = 0; j < 32; ++j) {
        const int cb = col_ids[c0 + j];            // sorted -> few changes
        if (cb != cur) { atomicAdd(&acc[cur], s); s = 0.f; cur = cb; }
        s += sp[j];
    }
    atomicAdd(&acc[cur], s);
    __syncthreads();

    if (tid < 64) {
        const int cb = tid;
        const float mean = acc[cb] / (cnts[rb] * cnts[64 + cb]);

        float h1[3], h2[3];
        #pragma unroll
        for (int j = 0; j < 3; ++j)
            h1[j] = fmaxf(mean * W1[j] + b1[j], 0.f);
        #pragma unroll
        for (int j = 0; j < 3; ++j) {
            float v = b2[j];
            #pragma unroll
            for (int i = 0; i < 3; ++i) v += h1[i] * W2[i * 3 + j];
            h2[j] = fmaxf(v, 0.f);
        }
        float z = b3[0];
        #pragma unroll
        for (int i = 0; i < 3; ++i) z += h2[i] * W3[i];

        out[rb * 64 + cb] = 1.0f / (1.0f + expf(-z));
    }
}

extern "C" void kernel_launch(void* const* d_in, const int* in_sizes, int n_in,
                              void* d_out, int out_size, void* d_ws, size_t ws_size,
                              hipStream_t stream) {
    const float* X       = (const float*)d_in[0];
    const int*   row_ids = (const int*)  d_in[1];
    const int*   col_ids = (const int*)  d_in[2];
    const float* W1      = (const float*)d_in[3];
    const float* b1      = (const float*)d_in[4];
    const float* W2      = (const float*)d_in[5];
    const float* b2      = (const float*)d_in[6];
    const float* W3      = (const float*)d_in[7];
    const float* b3      = (const float*)d_in[8];
    float* out = (float*)d_out;

    float* s1   = (float*)d_ws;                 // [64][8192] = 2 MiB
    float* cnts = s1 + (size_t)RB * NCOLS;      // [128] fp32 counts

    // ws is re-poisoned to 0xAA before every timed call -> zero s1 each call.
    hipMemsetAsync(d_ws, 0, (size_t)RB * NCOLS * sizeof(float), stream);

    counts_kernel<<<2, 256, 0, stream>>>(row_ids, col_ids, out, cnts);
    block_rowsum_kernel<<<dim3(8, 128), 256, 0, stream>>>(X, row_ids, s1);
    colreduce_mlp_kernel<<<64, 256, 0, stream>>>(s1, col_ids, cnts,
                                                 W1, b1, W2, b2, W3, b3, out);
}

// Round 2
// 387.306 us; speedup vs baseline: 1.0415x; 1.0415x over previous
//
#include <hip/hip_runtime.h>
#include <math.h>

#define NROWS 8192
#define NCOLS 8192
#define RB 64
#define CB 64

// ---------------------------------------------------------------------------
// Fused kernel: one pass over X -> global 64x64 block-sum accumulator.
// Grid: 1024 WGs x 256 threads. WG w owns rows [(w>>3)*64, +64) and cols
// [(w&7)*1024, +1024); each thread owns 4 consecutive cols (float4 loads,
// 1 KiB/wave/row fully coalesced).
//
// row_ids sorted -> row-block id is WG-uniform per row; accumulate the run in
// a register float4, flush on change: scatter the 4 cols into lds_acc[cb]
// (LDS float atomics, ~9 distinct col-blocks per 1024-col tile), then
// threads 0..63 atomicAdd the LDS slots into acc_g[cur*64 + cb]. ~2-3
// flushes per WG total -> ~30K global atomics over 4096 addresses.
//
// WGs 0 and 1 additionally compute the row/col histograms + cumsums first
// (32 KB of id reads; hidden under the 268 MB stream of the other WGs).
// ---------------------------------------------------------------------------
__global__ __launch_bounds__(256) void fused_blocksum_kernel(
    const float* __restrict__ X,
    const int*   __restrict__ row_ids,
    const int*   __restrict__ col_ids,
    float*       __restrict__ acc_g,   // ws: [64*64]
    float*       __restrict__ cnts,    // ws: [128] fp32 counts (row, col)
    float*       __restrict__ out)     // d_out (cumsums at [4096..4225])
{
    __shared__ int   rids[64];
    __shared__ float lacc[64];
    __shared__ int   hist[64];

    const int tid = threadIdx.x;
    const int bx  = blockIdx.x & 7;    // col tile 0..7
    const int by  = blockIdx.x >> 3;   // row chunk 0..127

    // ---- counts + cumsum (WGs 0 and 1 only; block-uniform branch) ----
    if (blockIdx.x < 2) {
        const int* ids = (blockIdx.x == 0) ? row_ids : col_ids;
        if (tid < 64) hist[tid] = 0;
        __syncthreads();
        for (int i = tid; i < NROWS; i += 256)
            atomicAdd(&hist[ids[i]], 1);
        __syncthreads();
        if (tid < 64) cnts[blockIdx.x * 64 + tid] = (float)hist[tid];
        if (tid == 0) {
            float* obase = out + RB * CB + blockIdx.x * (RB + 1);
            int c = 0;
            obase[0] = 0.0f;
            for (int i = 0; i < 64; ++i) { c += hist[i]; obase[i + 1] = (float)c; }
        }
        __syncthreads();
    }

    // ---- tile reduction ----
    if (tid < 64) {
        rids[tid] = row_ids[by * 64 + tid];
        lacc[tid] = 0.0f;
    }
    __syncthreads();

    const int c = bx * 1024 + tid * 4;
    const int4 cb4 = *(const int4*)(col_ids + c);      // col-block ids of my 4 cols
    const float* Xp = X + (size_t)by * 64 * NCOLS + c;

    float4 a = make_float4(0.f, 0.f, 0.f, 0.f);
    int cur = rids[0];

    #pragma unroll 4
    for (int i = 0; i < 64; ++i) {
        const int rb = rids[i];                         // WG-uniform
        if (rb != cur) {
            // flush register run -> LDS -> global (WG-uniform path)
            atomicAdd(&lacc[cb4.x], a.x);
            atomicAdd(&lacc[cb4.y], a.y);
            atomicAdd(&lacc[cb4.z], a.z);
            atomicAdd(&lacc[cb4.w], a.w);
            __syncthreads();
            if (tid < 64 && lacc[tid] != 0.0f)
                atomicAdd(&acc_g[cur * 64 + tid], lacc[tid]);
            __syncthreads();
            if (tid < 64) lacc[tid] = 0.0f;
            __syncthreads();
            a = make_float4(0.f, 0.f, 0.f, 0.f);
            cur = rb;
        }
        const float4 v = *(const float4*)(Xp + (size_t)i * NCOLS);
        a.x += v.x; a.y += v.y; a.z += v.z; a.w += v.w;
    }
    // final flush
    atomicAdd(&lacc[cb4.x], a.x);
    atomicAdd(&lacc[cb4.y], a.y);
    atomicAdd(&lacc[cb4.z], a.z);
    atomicAdd(&lacc[cb4.w], a.w);
    __syncthreads();
    if (tid < 64 && lacc[tid] != 0.0f)
        atomicAdd(&acc_g[cur * 64 + tid], lacc[tid]);
}

// ---------------------------------------------------------------------------
// Tiny epilogue: 4096 cells, mean -> 1->3->3->1 relu MLP -> sigmoid.
// ---------------------------------------------------------------------------
__global__ __launch_bounds__(256) void mlp_kernel(
    const float* __restrict__ acc_g,
    const float* __restrict__ cnts,
    const float* __restrict__ W1, const float* __restrict__ b1,
    const float* __restrict__ W2, const float* __restrict__ b2,
    const float* __restrict__ W3, const float* __restrict__ b3,
    float*       __restrict__ out)
{
    const int cell = blockIdx.x * 256 + threadIdx.x;   // 16 WGs * 256 = 4096
    const int rb = cell >> 6, cb = cell & 63;
    const float mean = acc_g[cell] / (cnts[rb] * cnts[64 + cb]);

    float h1[3], h2[3];
    #pragma unroll
    for (int j = 0; j < 3; ++j)
        h1[j] = fmaxf(mean * W1[j] + b1[j], 0.f);
    #pragma unroll
    for (int j = 0; j < 3; ++j) {
        float v = b2[j];
        #pragma unroll
        for (int i = 0; i < 3; ++i) v += h1[i] * W2[i * 3 + j];
        h2[j] = fmaxf(v, 0.f);
    }
    float z = b3[0];
    #pragma unroll
    for (int i = 0; i < 3; ++i) z += h2[i] * W3[i];

    out[cell] = 1.0f / (1.0f + expf(-z));
}

extern "C" void kernel_launch(void* const* d_in, const int* in_sizes, int n_in,
                              void* d_out, int out_size, void* d_ws, size_t ws_size,
                              hipStream_t stream) {
    const float* X       = (const float*)d_in[0];
    const int*   row_ids = (const int*)  d_in[1];
    const int*   col_ids = (const int*)  d_in[2];
    const float* W1      = (const float*)d_in[3];
    const float* b1      = (const float*)d_in[4];
    const float* W2      = (const float*)d_in[5];
    const float* b2      = (const float*)d_in[6];
    const float* W3      = (const float*)d_in[7];
    const float* b3      = (const float*)d_in[8];
    float* out = (float*)d_out;

    float* acc_g = (float*)d_ws;              // [4096]
    float* cnts  = acc_g + RB * CB;           // [128]

    // ws is re-poisoned to 0xAA each timed call -> zero the 16.9 KB we use.
    hipMemsetAsync(d_ws, 0, (RB * CB + 128) * sizeof(float), stream);

    fused_blocksum_kernel<<<1024, 256, 0, stream>>>(X, row_ids, col_ids,
                                                    acc_g, cnts, out);
    mlp_kernel<<<16, 256, 0, stream>>>(acc_g, cnts,
                                       W1, b1, W2, b2, W3, b3, out);
}